// Round 1
// baseline (5719.596 us; speedup 1.0000x reference)
//
#include <hip/hip_runtime.h>
#include <math.h>

// Problem constants
#define B_ 64
#define S_ 64
#define E_ 256
#define H_ 512
#define V_ 50000
#define T_ 32
#define SOS_ 1

// ---------------------------------------------------------------------------
// Setup kernels
// ---------------------------------------------------------------------------

// Build WbigT [2048][768]: row n = 4*j + c, col k in [0,768)
//  c=0 (r):  k<256 ? w_ih[j][k]      : w_hh[j][k-256]
//  c=1 (z):  k<256 ? w_ih[512+j][k]  : w_hh[512+j][k-256]
//  c=2 (in): k<256 ? w_ih[1024+j][k] : 0
//  c=3 (hn): k<256 ? 0               : w_hh[1024+j][k-256]
// biasBig[4j+c]: c0: b_ih[j]+b_hh[j]; c1: b_ih[512+j]+b_hh[512+j];
//                c2: b_ih[1024+j];    c3: b_hh[1024+j]
__global__ __launch_bounds__(256) void build_wbig(
    const float* __restrict__ w_ih, const float* __restrict__ w_hh,
    const float* __restrict__ b_ih, const float* __restrict__ b_hh,
    float* __restrict__ WbigT, float* __restrict__ biasBig)
{
    int g = blockIdx.x * 256 + threadIdx.x;
    if (g < 2048 * 768) {
        int n = g / 768, k = g % 768;
        int j = n >> 2, c = n & 3;
        float v = 0.f;
        if (c == 0)      v = (k < 256) ? w_ih[j * 256 + k]          : w_hh[j * 512 + (k - 256)];
        else if (c == 1) v = (k < 256) ? w_ih[(512 + j) * 256 + k]  : w_hh[(512 + j) * 512 + (k - 256)];
        else if (c == 2) v = (k < 256) ? w_ih[(1024 + j) * 256 + k] : 0.f;
        else             v = (k < 256) ? 0.f                        : w_hh[(1024 + j) * 512 + (k - 256)];
        WbigT[g] = v;
    }
    if (g < 2048) {
        int j = g >> 2, c = g & 3;
        float bv;
        if (c == 0)      bv = b_ih[j] + b_hh[j];
        else if (c == 1) bv = b_ih[512 + j] + b_hh[512 + j];
        else if (c == 2) bv = b_ih[1024 + j];
        else             bv = b_hh[1024 + j];
        biasBig[g] = bv;
    }
}

// awT[h][g] = attn_w[g][h]   (so q = h_new @ attn_w fits the W[N][K] GEMM form)
__global__ __launch_bounds__(256) void transpose_aw(
    const float* __restrict__ attn_w, float* __restrict__ awT)
{
    int idx = blockIdx.x * 256 + threadIdx.x;   // 512*512
    int h = idx >> 9, g = idx & 511;
    awT[idx] = attn_w[g * 512 + h];
}

// h0 <- encoder_hidden[0], dec_in <- SOS
__global__ __launch_bounds__(256) void init_state(
    const float* __restrict__ enc_hidden, float* __restrict__ hbuf0,
    int* __restrict__ dec_in)
{
    int idx = blockIdx.x * 256 + threadIdx.x;
    if (idx < B_ * H_) hbuf0[idx] = enc_hidden[idx];
    if (idx < B_) dec_in[idx] = SOS_;
}

// ---------------------------------------------------------------------------
// Generic 64x64x(K) fp32 tiled GEMM.  C[m][n] = sum_k A[m][k] * W[n][k]
// MODE 0: A(m,k) = k<256 ? emb[tok[m]][k] : hcur[m][k-256]  (gates; partials)
// MODE 1: A = plain [64][Kfull]; C = partials per K-chunk (blockIdx.y)
// MODE 2: A = plain, single K chunk; C[m*ldc + n] = acc + bias[n] (logits)
// ---------------------------------------------------------------------------
template <int MODE>
__global__ __launch_bounds__(256) void gemm64(
    const float* __restrict__ A, const float* __restrict__ W,
    float* __restrict__ C, const float* __restrict__ bias,
    int N, int Kfull, int kchunk,
    const float* __restrict__ emb, const int* __restrict__ tok,
    const float* __restrict__ hcur, long long ldc)
{
    __shared__ float As[64][68];   // [kk][m], stride 68 floats (16B-aligned rows)
    __shared__ float Ws[64][68];   // [kk][n]
    const int tid = threadIdx.x;
    const int n0 = blockIdx.x * 64;
    const int k0base = blockIdx.y * kchunk;
    const int tm = tid & 15;       // micro-tile rows   m = tm*4 .. tm*4+3
    const int tn = tid >> 4;       // micro-tile cols   n = tn*4 .. tn*4+3
    float acc[4][4] = {{0.f}};

    for (int kt = 0; kt < kchunk; kt += 64) {
        const int k0 = k0base + kt;
        // stage A tile (64 m x 64 k), transposed into As[kk][m]
        #pragma unroll
        for (int r = 0; r < 4; ++r) {
            int idx = tid + r * 256;
            int m = idx >> 4;
            int kk = (idx & 15) << 2;
            float4 v;
            if (MODE == 0) {
                int k = k0 + kk;
                if (k < 256) v = *(const float4*)&emb[(size_t)tok[m] * 256 + k];
                else         v = *(const float4*)&hcur[m * 512 + (k - 256)];
            } else {
                v = *(const float4*)&A[(size_t)m * Kfull + k0 + kk];
            }
            As[kk + 0][m] = v.x; As[kk + 1][m] = v.y;
            As[kk + 2][m] = v.z; As[kk + 3][m] = v.w;
        }
        // stage W tile (64 n x 64 k), transposed into Ws[kk][n]
        #pragma unroll
        for (int r = 0; r < 4; ++r) {
            int idx = tid + r * 256;
            int n = idx >> 4;
            int kk = (idx & 15) << 2;
            int row = n0 + n;
            float4 v = make_float4(0.f, 0.f, 0.f, 0.f);
            if (MODE != 2 || row < N)
                v = *(const float4*)&W[(size_t)row * Kfull + k0 + kk];
            Ws[kk + 0][n] = v.x; Ws[kk + 1][n] = v.y;
            Ws[kk + 2][n] = v.z; Ws[kk + 3][n] = v.w;
        }
        __syncthreads();
        #pragma unroll
        for (int kk = 0; kk < 64; ++kk) {
            float4 a = *(const float4*)&As[kk][tm << 2];
            float4 w = *(const float4*)&Ws[kk][tn << 2];
            acc[0][0] += a.x * w.x; acc[0][1] += a.x * w.y;
            acc[0][2] += a.x * w.z; acc[0][3] += a.x * w.w;
            acc[1][0] += a.y * w.x; acc[1][1] += a.y * w.y;
            acc[1][2] += a.y * w.z; acc[1][3] += a.y * w.w;
            acc[2][0] += a.z * w.x; acc[2][1] += a.z * w.y;
            acc[2][2] += a.z * w.z; acc[2][3] += a.z * w.w;
            acc[3][0] += a.w * w.x; acc[3][1] += a.w * w.y;
            acc[3][2] += a.w * w.z; acc[3][3] += a.w * w.w;
        }
        __syncthreads();
    }

    if (MODE == 2) {
        #pragma unroll
        for (int i = 0; i < 4; ++i) {
            int m = (tm << 2) + i;
            #pragma unroll
            for (int j2 = 0; j2 < 4; ++j2) {
                int v = n0 + (tn << 2) + j2;
                if (v < N) C[(long long)m * ldc + v] = acc[i][j2] + bias[v];
            }
        }
    } else {
        float* Cp = C + (size_t)blockIdx.y * 64 * N;
        #pragma unroll
        for (int i = 0; i < 4; ++i) {
            int m = (tm << 2) + i;
            #pragma unroll
            for (int j2 = 0; j2 < 4; ++j2) {
                Cp[(size_t)m * N + n0 + (tn << 2) + j2] = acc[i][j2];
            }
        }
    }
}

// ---------------------------------------------------------------------------
// GRU gate combine: h_new = (1-z)*n + z*h ;  writes hnxt and concatA[:, :512]
// gatesP: [3][64][2048] partials (columns interleaved 4j+{r,z,in,hn})
// ---------------------------------------------------------------------------
__global__ __launch_bounds__(512) void combine_kernel(
    const float* __restrict__ gP, const float* __restrict__ bb,
    const float* __restrict__ hcur, float* __restrict__ hnxt,
    float* __restrict__ concatA)
{
    int idx = blockIdx.x * 512 + threadIdx.x;   // 64*512
    int b = idx >> 9, j = idx & 511;
    int base = b * 2048 + (j << 2);
    const int SP = 64 * 2048;
    float g0 = gP[base + 0] + gP[SP + base + 0] + gP[2 * SP + base + 0] + bb[(j << 2) + 0];
    float g1 = gP[base + 1] + gP[SP + base + 1] + gP[2 * SP + base + 1] + bb[(j << 2) + 1];
    float g2 = gP[base + 2] + gP[SP + base + 2] + gP[2 * SP + base + 2] + bb[(j << 2) + 2];
    float g3 = gP[base + 3] + gP[SP + base + 3] + gP[2 * SP + base + 3] + bb[(j << 2) + 3];
    float r = 1.f / (1.f + expf(-g0));
    float z = 1.f / (1.f + expf(-g1));
    float n = tanhf(g2 + r * g3);
    float hv = hcur[idx];
    float h2 = (1.f - z) * n + z * hv;
    hnxt[idx] = h2;
    concatA[b * 1024 + j] = h2;
}

// ---------------------------------------------------------------------------
// Per-b attention: scores = q . enc[b,s,:], softmax over s, context -> concatA
// qP: [2][64][512] K-split partials of q = h_new @ attn_w
// ---------------------------------------------------------------------------
__global__ __launch_bounds__(512) void attn_kernel(
    const float* __restrict__ qP, const float* __restrict__ enc,
    float* __restrict__ concatA)
{
    int b = blockIdx.x;
    int tid = threadIdx.x;
    __shared__ float q[512];
    __shared__ float aw[64];
    q[tid] = qP[b * 512 + tid] + qP[64 * 512 + b * 512 + tid];
    __syncthreads();

    int wv = tid >> 6, ln = tid & 63;
    #pragma unroll
    for (int si = 0; si < 8; ++si) {
        int s = (wv << 3) + si;
        const float* er = enc + ((size_t)(b * 64 + s)) * 512;
        float p = 0.f;
        #pragma unroll
        for (int i = 0; i < 8; ++i) p += q[ln + (i << 6)] * er[ln + (i << 6)];
        for (int off = 32; off; off >>= 1) p += __shfl_down(p, off);
        if (ln == 0) aw[s] = p;
    }
    __syncthreads();
    if (tid < 64) {
        float v = aw[tid], m = v;
        for (int off = 32; off; off >>= 1) m = fmaxf(m, __shfl_xor(m, off));
        float e = expf(v - m);
        float ssum = e;
        for (int off = 32; off; off >>= 1) ssum += __shfl_xor(ssum, off);
        aw[tid] = e / ssum;
    }
    __syncthreads();
    float c = 0.f;
    const float* eb = enc + (size_t)b * 64 * 512 + tid;
    for (int s = 0; s < 64; ++s) c += aw[s] * eb[s * 512];
    concatA[b * 1024 + 512 + tid] = c;
}

// Abuf = tanh(sum of 4 concat-GEMM partials)
__global__ __launch_bounds__(512) void tanh_combine(
    const float* __restrict__ cgP, float* __restrict__ Abuf)
{
    int idx = blockIdx.x * 512 + threadIdx.x;   // 64*512
    const int SP = 64 * 512;
    float v = cgP[idx] + cgP[SP + idx] + cgP[2 * SP + idx] + cgP[3 * SP + idx];
    Abuf[idx] = tanhf(v);
}

// ---------------------------------------------------------------------------
// log_softmax (in-place over out[b][t][:]) + argmax -> dec_in
// ---------------------------------------------------------------------------
__global__ __launch_bounds__(1024) void lsm_kernel(
    float* __restrict__ out, int t, int* __restrict__ dec_in)
{
    int b = blockIdx.x;
    int tid = threadIdx.x;
    float* row = out + (size_t)b * T_ * V_ + (size_t)t * V_;
    __shared__ float sv[1024];
    __shared__ int si_[1024];

    // pass 1: max + argmax (first occurrence wins)
    float lm = -INFINITY;
    int li = 0;
    for (int v = tid; v < V_; v += 1024) {
        float x = row[v];
        if (x > lm) { lm = x; li = v; }
    }
    sv[tid] = lm; si_[tid] = li;
    __syncthreads();
    for (int s = 512; s; s >>= 1) {
        if (tid < s) {
            float o = sv[tid + s]; int oi = si_[tid + s];
            if (o > sv[tid] || (o == sv[tid] && oi < si_[tid])) { sv[tid] = o; si_[tid] = oi; }
        }
        __syncthreads();
    }
    float M = sv[0];
    int amax = si_[0];
    __syncthreads();

    // pass 2: sum exp
    float ls = 0.f;
    for (int v = tid; v < V_; v += 1024) ls += expf(row[v] - M);
    sv[tid] = ls;
    __syncthreads();
    for (int s = 512; s; s >>= 1) {
        if (tid < s) sv[tid] += sv[tid + s];
        __syncthreads();
    }
    float logZ = M + logf(sv[0]);

    // pass 3: normalize in place
    for (int v = tid; v < V_; v += 1024) row[v] -= logZ;
    if (tid == 0) dec_in[b] = amax;
}

__global__ __launch_bounds__(256) void final_copy(
    const float* __restrict__ hfin, float* __restrict__ dst)
{
    int idx = blockIdx.x * 256 + threadIdx.x;
    if (idx < B_ * H_) dst[idx] = hfin[idx];
}

// ---------------------------------------------------------------------------
extern "C" void kernel_launch(void* const* d_in, const int* in_sizes, int n_in,
                              void* d_out, int out_size, void* d_ws, size_t ws_size,
                              hipStream_t stream)
{
    const float* enc_hidden = (const float*)d_in[0];
    // d_in[1] target, d_in[2] target_length: unused (greedy decoding)
    const float* enc    = (const float*)d_in[3];
    const float* emb    = (const float*)d_in[4];
    const float* w_ih   = (const float*)d_in[5];
    const float* w_hh   = (const float*)d_in[6];
    const float* b_ih   = (const float*)d_in[7];
    const float* b_hh   = (const float*)d_in[8];
    const float* attn_w = (const float*)d_in[9];
    const float* Wa     = (const float*)d_in[10];
    const float* fc_w   = (const float*)d_in[11];
    const float* fc_b   = (const float*)d_in[12];
    float* out = (float*)d_out;
    float* ws  = (float*)d_ws;

    float* WbigT   = ws;                     // 2048*768  = 1,572,864
    float* biasBig = WbigT + 1572864;        // 2048
    float* awT     = biasBig + 2048;         // 512*512   = 262,144
    float* hbuf0   = awT + 262144;           // 32768
    float* hbuf1   = hbuf0 + 32768;          // 32768
    float* gatesP  = hbuf1 + 32768;          // 3*64*2048 = 393,216
    float* qP      = gatesP + 393216;        // 2*64*512  = 65,536
    float* concatA = qP + 65536;             // 64*1024   = 65,536
    float* cgP     = concatA + 65536;        // 4*64*512  = 131,072
    float* Abuf    = cgP + 131072;           // 32768
    int*   dec_in  = (int*)(Abuf + 32768);   // 64 ints

    build_wbig<<<6144, 256, 0, stream>>>(w_ih, w_hh, b_ih, b_hh, WbigT, biasBig);
    transpose_aw<<<1024, 256, 0, stream>>>(attn_w, awT);
    init_state<<<128, 256, 0, stream>>>(enc_hidden, hbuf0, dec_in);

    for (int t = 0; t < T_; ++t) {
        float* hcur = (t & 1) ? hbuf1 : hbuf0;
        float* hnxt = (t & 1) ? hbuf0 : hbuf1;

        // gates = [x|h] @ WbigT^T   (K=768 split into 3 chunks of 256)
        gemm64<0><<<dim3(32, 3), 256, 0, stream>>>(
            nullptr, WbigT, gatesP, nullptr, 2048, 768, 256,
            emb, dec_in, hcur, 0);

        combine_kernel<<<64, 512, 0, stream>>>(gatesP, biasBig, hcur, hnxt, concatA);

        // q = h_new @ attn_w   (K=512 split into 2)
        gemm64<1><<<dim3(8, 2), 256, 0, stream>>>(
            hnxt, awT, qP, nullptr, 512, 512, 256,
            nullptr, nullptr, nullptr, 0);

        attn_kernel<<<64, 512, 0, stream>>>(qP, enc, concatA);

        // concat_out_pre = [h_new|ctx] @ Wa^T   (K=1024 split into 4)
        gemm64<1><<<dim3(8, 4), 256, 0, stream>>>(
            concatA, Wa, cgP, nullptr, 512, 1024, 256,
            nullptr, nullptr, nullptr, 0);

        tanh_combine<<<64, 512, 0, stream>>>(cgP, Abuf);

        // logits = Abuf @ fc_w^T + fc_b  -> raw logits written into d_out
        gemm64<2><<<dim3(782, 1), 256, 0, stream>>>(
            Abuf, fc_w, out + (size_t)t * V_, fc_b, V_, 512, 512,
            nullptr, nullptr, nullptr, (long long)T_ * V_);

        lsm_kernel<<<64, 1024, 0, stream>>>(out, t, dec_in);
    }

    final_copy<<<128, 256, 0, stream>>>(hbuf0, out + (size_t)B_ * T_ * V_);
}